// Round 1
// baseline (3014.365 us; speedup 1.0000x reference)
//
#include <hip/hip_runtime.h>
#include <math.h>

// Problem constants
constexpr int B  = 128;
constexpr int T  = 1024;
constexpr int IN_DIM = 32;
constexpr int D  = 128;
constexpr int H  = 8;
constexpr int DH = 16;   // D/H
constexpr int L  = 2;
constexpr int U  = 34;   // int(5*ln(1025))
constexpr int FF = 512;  // 4*D

// ---------------- helpers ----------------

__device__ __forceinline__ float blockMax256(float v, float* red) {
  for (int off = 32; off; off >>= 1) v = fmaxf(v, __shfl_down(v, off));
  if ((threadIdx.x & 63) == 0) red[threadIdx.x >> 6] = v;
  __syncthreads();
  v = fmaxf(fmaxf(red[0], red[1]), fmaxf(red[2], red[3]));
  __syncthreads();
  return v;
}

__device__ __forceinline__ float blockSum256(float v, float* red) {
  for (int off = 32; off; off >>= 1) v += __shfl_down(v, off);
  if ((threadIdx.x & 63) == 0) red[threadIdx.x >> 6] = v;
  __syncthreads();
  v = red[0] + red[1] + red[2] + red[3];
  __syncthreads();
  return v;
}

// ---------------- kernels ----------------

// h[b,t,:] = x[b,t,:] @ proj_w + proj_b + pos_enc(t,:)
__global__ __launch_bounds__(D) void k_proj(const float* __restrict__ x,
                                            const float* __restrict__ pw,
                                            const float* __restrict__ pb,
                                            float* __restrict__ h) {
  int row = blockIdx.x;            // b*T + t
  int t = row & (T - 1);
  int d = threadIdx.x;
  __shared__ float xs[IN_DIM];
  if (threadIdx.x < IN_DIM) xs[threadIdx.x] = x[(size_t)row * IN_DIM + threadIdx.x];
  __syncthreads();
  float acc = pb[d];
#pragma unroll
  for (int i = 0; i < IN_DIM; ++i) acc += xs[i] * pw[i * D + d];
  int j = d >> 1;
  float div = expf((float)(2 * j) * (-logf(10000.f) / (float)D));
  float ang = (float)t * div;
  acc += (d & 1) ? cosf(ang) : sinf(ang);
  h[(size_t)row * D + d] = acc;
}

// C[M,128] = A[M,128] @ W[128,128]  (no bias).  32 rows per block.
__global__ __launch_bounds__(256) void k_gemm128(const float* __restrict__ A,
                                                 const float* __restrict__ W,
                                                 float* __restrict__ C) {
  __shared__ float As[32][D];
  int r0 = blockIdx.x * 32;
  for (int i = threadIdx.x; i < 32 * D; i += 256)
    As[i / D][i % D] = A[(size_t)(r0 + i / D) * D + (i % D)];
  __syncthreads();
  int d = threadIdx.x & 127;
  int half = threadIdx.x >> 7;   // 0 or 1 -> rows [half*16, +16)
  float acc[16];
#pragma unroll
  for (int r = 0; r < 16; ++r) acc[r] = 0.f;
  for (int k = 0; k < D; ++k) {
    float w = W[k * D + d];
#pragma unroll
    for (int r = 0; r < 16; ++r) acc[r] += As[half * 16 + r][k] * w;
  }
#pragma unroll
  for (int r = 0; r < 16; ++r)
    C[(size_t)(r0 + half * 16 + r) * D + d] = acc[r];
}

// qs[b,u,:] = h[b, idx[u], :] @ wq
__global__ __launch_bounds__(D) void k_qrow(const float* __restrict__ h,
                                            const int* __restrict__ idx,
                                            const float* __restrict__ wq,
                                            float* __restrict__ qs) {
  int bu = blockIdx.x;             // b*U + u
  int b = bu / U, u = bu - b * U;
  int t = idx[u];
  __shared__ float hs[D];
  hs[threadIdx.x] = h[((size_t)b * T + t) * D + threadIdx.x];
  __syncthreads();
  int d = threadIdx.x;
  float acc = 0.f;
  for (int k = 0; k < D; ++k) acc += hs[k] * wq[k * D + d];
  qs[(size_t)bu * D + d] = acc;
}

// ctx[b,u,h*16+dh] = softmax(qs.k^T/4) @ v      one block per (b,h,u)
__global__ __launch_bounds__(256) void k_attn(const float* __restrict__ qs,
                                              const float* __restrict__ kbuf,
                                              const float* __restrict__ vbuf,
                                              float* __restrict__ ctx) {
  int id = blockIdx.x;
  int u = id % U; int bh = id / U; int hh = bh % H; int b = bh / H;
  __shared__ float sc[T];
  __shared__ float qv[DH];
  __shared__ float red[4];
  if (threadIdx.x < DH)
    qv[threadIdx.x] = qs[((size_t)b * U + u) * D + hh * DH + threadIdx.x];
  __syncthreads();
  float lmax = -1e30f;
  for (int t = threadIdx.x; t < T; t += 256) {
    const float* kp = kbuf + ((size_t)b * T + t) * D + hh * DH;
    float s = 0.f;
#pragma unroll
    for (int dh = 0; dh < DH; ++dh) s += qv[dh] * kp[dh];
    s *= 0.25f;                       // 1/sqrt(16)
    sc[t] = s;
    lmax = fmaxf(lmax, s);
  }
  float gmax = blockMax256(lmax, red);
  float lsum = 0.f;
  for (int t = threadIdx.x; t < T; t += 256) {
    float e = expf(sc[t] - gmax);
    sc[t] = e;
    lsum += e;
  }
  float gsum = blockSum256(lsum, red);
  float inv = 1.f / gsum;
  float part[DH];
#pragma unroll
  for (int dh = 0; dh < DH; ++dh) part[dh] = 0.f;
  for (int t = threadIdx.x; t < T; t += 256) {
    const float* vp = vbuf + ((size_t)b * T + t) * D + hh * DH;
    float a = sc[t];
#pragma unroll
    for (int dh = 0; dh < DH; ++dh) part[dh] += a * vp[dh];
  }
  for (int dh = 0; dh < DH; ++dh) {
    float tot = blockSum256(part[dh], red);
    if (threadIdx.x == 0)
      ctx[((size_t)b * U + u) * D + hh * DH + dh] = tot * inv;
  }
}

// baseo[b,:] = (mean_u ctx[b,u,:]) @ wo + wo_b
__global__ __launch_bounds__(D) void k_base(const float* __restrict__ ctx,
                                            const float* __restrict__ wo,
                                            const float* __restrict__ wob,
                                            float* __restrict__ baseo) {
  int b = blockIdx.x, d = threadIdx.x;
  __shared__ float bc[D];
  float s = 0.f;
  for (int u = 0; u < U; ++u) s += ctx[((size_t)b * U + u) * D + d];
  bc[d] = s * (1.f / (float)U);
  __syncthreads();
  float acc = wob[d];
  for (int k = 0; k < D; ++k) acc += bc[k] * wo[k * D + d];
  baseo[(size_t)b * D + d] = acc;
}

// ctxo[b,u,:] = ctx[b,u,:] @ wo + wo_b
__global__ __launch_bounds__(D) void k_crow(const float* __restrict__ ctx,
                                            const float* __restrict__ wo,
                                            const float* __restrict__ wob,
                                            float* __restrict__ ctxo) {
  int bu = blockIdx.x, d = threadIdx.x;
  __shared__ float cs[D];
  cs[d] = ctx[(size_t)bu * D + d];
  __syncthreads();
  float acc = wob[d];
  for (int k = 0; k < D; ++k) acc += cs[k] * wo[k * D + d];
  ctxo[(size_t)bu * D + d] = acc;
}

// map[t] = u such that idx[u]==t, else -1
__global__ void k_map(const int* __restrict__ idx, int* __restrict__ map) {
  int t = blockIdx.x * 256 + threadIdx.x;
  if (t >= T) return;
  int m = -1;
  for (int u = 0; u < U; ++u)
    if (idx[u] == t) m = u;
  map[t] = m;
}

// h = LN(h + attn_out)   one block (128 thr) per row
__global__ __launch_bounds__(D) void k_ln1(float* __restrict__ h,
                                           const float* __restrict__ ctxo,
                                           const float* __restrict__ baseo,
                                           const int* __restrict__ map,
                                           const float* __restrict__ g,
                                           const float* __restrict__ bb) {
  int row = blockIdx.x;            // b*T + t
  int b = row >> 10, t = row & (T - 1);
  int d = threadIdx.x;
  int u = map[t];
  float add = (u >= 0) ? ctxo[((size_t)b * U + u) * D + d]
                       : baseo[(size_t)b * D + d];
  float y = h[(size_t)row * D + d] + add;
  __shared__ float red[2];
  float s = y;
  for (int off = 32; off; off >>= 1) s += __shfl_down(s, off);
  if ((threadIdx.x & 63) == 0) red[threadIdx.x >> 6] = s;
  __syncthreads();
  float m = (red[0] + red[1]) * (1.f / D);
  __syncthreads();
  float e = y - m;
  float v = e * e;
  for (int off = 32; off; off >>= 1) v += __shfl_down(v, off);
  if ((threadIdx.x & 63) == 0) red[threadIdx.x >> 6] = v;
  __syncthreads();
  float inv = rsqrtf((red[0] + red[1]) * (1.f / D) + 1e-5f);
  h[(size_t)row * D + d] = e * inv * g[d] + bb[d];
}

// Fused FF + residual + LN2, 16 rows per block (in-place on h)
constexpr int RF = 16;
__global__ __launch_bounds__(256) void k_ff(float* __restrict__ h,
                                            const float* __restrict__ w1,
                                            const float* __restrict__ b1,
                                            const float* __restrict__ w2,
                                            const float* __restrict__ b2,
                                            const float* __restrict__ g,
                                            const float* __restrict__ bb) {
  __shared__ float hs[RF][D];
  __shared__ float tmp[RF][FF];
  __shared__ float mv[RF][2];
  int r0 = blockIdx.x * RF;
  for (int i = threadIdx.x; i < RF * D; i += 256)
    hs[i / D][i % D] = h[(size_t)(r0 + i / D) * D + (i % D)];
  __syncthreads();
  // phase 1: tmp = gelu(hs @ w1 + b1)
  for (int jj = 0; jj < FF / 256; ++jj) {
    int j = jj * 256 + threadIdx.x;
    float acc[RF];
#pragma unroll
    for (int r = 0; r < RF; ++r) acc[r] = 0.f;
    for (int k = 0; k < D; ++k) {
      float w = w1[k * FF + j];
#pragma unroll
      for (int r = 0; r < RF; ++r) acc[r] += hs[r][k] * w;
    }
    float bj = b1[j];
#pragma unroll
    for (int r = 0; r < RF; ++r) {
      float v = acc[r] + bj;
      tmp[r][j] = 0.5f * v * (1.f + erff(v * 0.70710678118654752f));
    }
  }
  __syncthreads();
  // phase 2: y = hs + tmp @ w2 + b2
  int d = threadIdx.x & 127, half = threadIdx.x >> 7;
  float acc2[RF / 2];
#pragma unroll
  for (int r = 0; r < RF / 2; ++r) acc2[r] = 0.f;
  for (int k = 0; k < FF; ++k) {
    float w = w2[k * D + d];
#pragma unroll
    for (int r = 0; r < RF / 2; ++r) acc2[r] += tmp[half * (RF / 2) + r][k] * w;
  }
  __syncthreads();                       // done reading tmp; reuse as ys
  float* ys = &tmp[0][0];
  float bd = b2[d];
#pragma unroll
  for (int r = 0; r < RF / 2; ++r) {
    int rr = half * (RF / 2) + r;
    ys[rr * D + d] = hs[rr][d] + acc2[r] + bd;
  }
  __syncthreads();
  // LN2: 16 threads per row
  int row = threadIdx.x >> 4, lane = threadIdx.x & 15;
  float s = 0.f;
  for (int dd = lane; dd < D; dd += 16) s += ys[row * D + dd];
  for (int off = 8; off; off >>= 1) s += __shfl_down(s, off, 16);
  if (lane == 0) mv[row][0] = s * (1.f / D);
  __syncthreads();
  float m = mv[row][0];
  float v2 = 0.f;
  for (int dd = lane; dd < D; dd += 16) {
    float e = ys[row * D + dd] - m;
    v2 += e * e;
  }
  for (int off = 8; off; off >>= 1) v2 += __shfl_down(v2, off, 16);
  if (lane == 0) mv[row][1] = rsqrtf(v2 * (1.f / D) + 1e-5f);
  __syncthreads();
  for (int i = threadIdx.x; i < RF * D; i += 256) {
    int r = i / D, dd = i % D;
    h[(size_t)(r0 + r) * D + dd] = (ys[i] - mv[r][0]) * mv[r][1] * g[dd] + bb[dd];
  }
}

// out[b] = LN(h[b,T-1,:]) @ head_w + head_wb
__global__ __launch_bounds__(D) void k_head(const float* __restrict__ h,
                                            const float* __restrict__ g,
                                            const float* __restrict__ bb,
                                            const float* __restrict__ hw,
                                            const float* __restrict__ hwb,
                                            float* __restrict__ out) {
  int b = blockIdx.x, d = threadIdx.x;
  float y = h[((size_t)b * T + (T - 1)) * D + d];
  __shared__ float red[2];
  float s = y;
  for (int off = 32; off; off >>= 1) s += __shfl_down(s, off);
  if ((threadIdx.x & 63) == 0) red[threadIdx.x >> 6] = s;
  __syncthreads();
  float m = (red[0] + red[1]) * (1.f / D);
  __syncthreads();
  float e = y - m;
  float v = e * e;
  for (int off = 32; off; off >>= 1) v += __shfl_down(v, off);
  if ((threadIdx.x & 63) == 0) red[threadIdx.x >> 6] = v;
  __syncthreads();
  float inv = rsqrtf((red[0] + red[1]) * (1.f / D) + 1e-5f);
  __syncthreads();
  float last = e * inv * g[d] + bb[d];
  float p = last * hw[d];
  for (int off = 32; off; off >>= 1) p += __shfl_down(p, off);
  if ((threadIdx.x & 63) == 0) red[threadIdx.x >> 6] = p;
  __syncthreads();
  if (threadIdx.x == 0) out[b] = red[0] + red[1] + hwb[0];
}

// ---------------- launch ----------------

extern "C" void kernel_launch(void* const* d_in, const int* in_sizes, int n_in,
                              void* d_out, int out_size, void* d_ws, size_t ws_size,
                              hipStream_t stream) {
  const float* x       = (const float*)d_in[0];
  const int*   idx     = (const int*)d_in[1];
  const float* proj_w  = (const float*)d_in[2];
  const float* proj_b  = (const float*)d_in[3];
  const float* wq      = (const float*)d_in[4];
  const float* wk      = (const float*)d_in[5];
  const float* wv      = (const float*)d_in[6];
  const float* wo      = (const float*)d_in[7];
  const float* wo_b    = (const float*)d_in[8];
  const float* ln1_g   = (const float*)d_in[9];
  const float* ln1_b   = (const float*)d_in[10];
  const float* ff1_w   = (const float*)d_in[11];
  const float* ff1_b   = (const float*)d_in[12];
  const float* ff2_w   = (const float*)d_in[13];
  const float* ff2_b   = (const float*)d_in[14];
  const float* ln2_g   = (const float*)d_in[15];
  const float* ln2_b   = (const float*)d_in[16];
  const float* head_g  = (const float*)d_in[17];
  const float* head_bb = (const float*)d_in[18];
  const float* head_w  = (const float*)d_in[19];
  const float* head_wb = (const float*)d_in[20];
  float* out = (float*)d_out;

  float* wsf  = (float*)d_ws;
  float* h    = wsf;
  float* kbuf = h    + (size_t)B * T * D;
  float* vbuf = kbuf + (size_t)B * T * D;
  float* qs   = vbuf + (size_t)B * T * D;
  float* ctx  = qs   + (size_t)B * U * D;
  float* ctxo = ctx  + (size_t)B * U * D;
  float* baseo= ctxo + (size_t)B * U * D;
  int*   map  = (int*)(baseo + (size_t)B * D);

  k_proj<<<B * T, D, 0, stream>>>(x, proj_w, proj_b, h);

  for (int l = 0; l < L; ++l) {
    const float* wq_l = wq + (size_t)l * D * D;
    const float* wk_l = wk + (size_t)l * D * D;
    const float* wv_l = wv + (size_t)l * D * D;
    const float* wo_l = wo + (size_t)l * D * D;
    const int*   idx_l = idx + l * U;

    k_gemm128<<<B * T / 32, 256, 0, stream>>>(h, wk_l, kbuf);
    k_gemm128<<<B * T / 32, 256, 0, stream>>>(h, wv_l, vbuf);
    k_qrow<<<B * U, D, 0, stream>>>(h, idx_l, wq_l, qs);
    k_attn<<<B * H * U, 256, 0, stream>>>(qs, kbuf, vbuf, ctx);
    k_base<<<B, D, 0, stream>>>(ctx, wo_l, wo_b + l * D, baseo);
    k_crow<<<B * U, D, 0, stream>>>(ctx, wo_l, wo_b + l * D, ctxo);
    k_map<<<(T + 255) / 256, 256, 0, stream>>>(idx_l, map);
    k_ln1<<<B * T, D, 0, stream>>>(h, ctxo, baseo, map,
                                   ln1_g + l * D, ln1_b + l * D);
    k_ff<<<B * T / RF, 256, 0, stream>>>(h, ff1_w + (size_t)l * D * FF,
                                         ff1_b + l * FF,
                                         ff2_w + (size_t)l * FF * D,
                                         ff2_b + l * D,
                                         ln2_g + l * D, ln2_b + l * D);
  }

  k_head<<<B, D, 0, stream>>>(h, head_g, head_bb, head_w, head_wb, out);
}

// Round 5
// 2474.405 us; speedup vs baseline: 1.2182x; 1.2182x over previous
//
#include <hip/hip_runtime.h>
#include <math.h>

// Problem constants
constexpr int B  = 128;
constexpr int T  = 1024;
constexpr int IN_DIM = 32;
constexpr int D  = 128;
constexpr int H  = 8;
constexpr int DH = 16;   // D/H
constexpr int L  = 2;
constexpr int U  = 34;   // int(5*ln(1025))
constexpr int FF = 512;  // 4*D

typedef __attribute__((ext_vector_type(8))) _Float16 f16x8;
typedef __attribute__((ext_vector_type(4))) float f32x4;

__device__ __forceinline__ unsigned short f2h(float x) {
  union { _Float16 h; unsigned short u; } v;
  v.h = (_Float16)x;
  return v.u;
}

// ---------------- helpers ----------------

__device__ __forceinline__ float blockMax256(float v, float* red) {
  for (int off = 32; off; off >>= 1) v = fmaxf(v, __shfl_down(v, off));
  if ((threadIdx.x & 63) == 0) red[threadIdx.x >> 6] = v;
  __syncthreads();
  v = fmaxf(fmaxf(red[0], red[1]), fmaxf(red[2], red[3]));
  __syncthreads();
  return v;
}

__device__ __forceinline__ float blockSum256(float v, float* red) {
  for (int off = 32; off; off >>= 1) v += __shfl_down(v, off);
  if ((threadIdx.x & 63) == 0) red[threadIdx.x >> 6] = v;
  __syncthreads();
  v = red[0] + red[1] + red[2] + red[3];
  __syncthreads();
  return v;
}

// ---------------- kernels ----------------

// Transpose + f32->f16: out[n*K+k] = f16(in[k*N+n])
__global__ void k_prep(const float* __restrict__ in, unsigned short* __restrict__ out,
                       int K, int N) {
  int t = blockIdx.x * 256 + threadIdx.x;
  if (t >= K * N) return;
  int n = t / K, k = t - n * K;
  out[t] = f2h(in[(size_t)k * N + n]);
}

// h[b,t,:] = x[b,t,:] @ proj_w + proj_b + pos_enc(t,:)
__global__ __launch_bounds__(D) void k_proj(const float* __restrict__ x,
                                            const float* __restrict__ pw,
                                            const float* __restrict__ pb,
                                            float* __restrict__ h) {
  int row = blockIdx.x;            // b*T + t
  int t = row & (T - 1);
  int d = threadIdx.x;
  __shared__ float xs[IN_DIM];
  if (threadIdx.x < IN_DIM) xs[threadIdx.x] = x[(size_t)row * IN_DIM + threadIdx.x];
  __syncthreads();
  float acc = pb[d];
#pragma unroll
  for (int i = 0; i < IN_DIM; ++i) acc += xs[i] * pw[i * D + d];
  int j = d >> 1;
  float div = expf((float)(2 * j) * (-logf(10000.f) / (float)D));
  float ang = (float)t * div;
  acc += (d & 1) ? cosf(ang) : sinf(ang);
  h[(size_t)row * D + d] = acc;
}

// C[M,128] = A[M,128] @ W[128,128]  (no bias).  32 rows per block.  (f32, known-good)
__global__ __launch_bounds__(256) void k_gemm128(const float* __restrict__ A,
                                                 const float* __restrict__ W,
                                                 float* __restrict__ C) {
  __shared__ float As[32][D];
  int r0 = blockIdx.x * 32;
  for (int i = threadIdx.x; i < 32 * D; i += 256)
    As[i / D][i % D] = A[(size_t)(r0 + i / D) * D + (i % D)];
  __syncthreads();
  int d = threadIdx.x & 127;
  int half = threadIdx.x >> 7;   // 0 or 1 -> rows [half*16, +16)
  float acc[16];
#pragma unroll
  for (int r = 0; r < 16; ++r) acc[r] = 0.f;
  for (int k = 0; k < D; ++k) {
    float w = W[k * D + d];
#pragma unroll
    for (int r = 0; r < 16; ++r) acc[r] += As[half * 16 + r][k] * w;
  }
#pragma unroll
  for (int r = 0; r < 16; ++r)
    C[(size_t)(r0 + half * 16 + r) * D + d] = acc[r];
}

// qs[b,u,:] = h[b, idx[u], :] @ wq
__global__ __launch_bounds__(D) void k_qrow(const float* __restrict__ h,
                                            const int* __restrict__ idx,
                                            const float* __restrict__ wq,
                                            float* __restrict__ qs) {
  int bu = blockIdx.x;             // b*U + u
  int b = bu / U, u = bu - b * U;
  int t = idx[u];
  __shared__ float hs[D];
  hs[threadIdx.x] = h[((size_t)b * T + t) * D + threadIdx.x];
  __syncthreads();
  int d = threadIdx.x;
  float acc = 0.f;
  for (int k = 0; k < D; ++k) acc += hs[k] * wq[k * D + d];
  qs[(size_t)bu * D + d] = acc;
}

// ctx[b,u,h*16+dh] = softmax(qs.k^T/4) @ v      one block per (b,h,u)
__global__ __launch_bounds__(256) void k_attn(const float* __restrict__ qs,
                                              const float* __restrict__ kbuf,
                                              const float* __restrict__ vbuf,
                                              float* __restrict__ ctx) {
  int id = blockIdx.x;
  int u = id % U; int bh = id / U; int hh = bh % H; int b = bh / H;
  __shared__ float sc[T];
  __shared__ float qv[DH];
  __shared__ float red[4];
  if (threadIdx.x < DH)
    qv[threadIdx.x] = qs[((size_t)b * U + u) * D + hh * DH + threadIdx.x];
  __syncthreads();
  float lmax = -1e30f;
  for (int t = threadIdx.x; t < T; t += 256) {
    const float* kp = kbuf + ((size_t)b * T + t) * D + hh * DH;
    float s = 0.f;
#pragma unroll
    for (int dh = 0; dh < DH; ++dh) s += qv[dh] * kp[dh];
    s *= 0.25f;                       // 1/sqrt(16)
    sc[t] = s;
    lmax = fmaxf(lmax, s);
  }
  float gmax = blockMax256(lmax, red);
  float lsum = 0.f;
  for (int t = threadIdx.x; t < T; t += 256) {
    float e = expf(sc[t] - gmax);
    sc[t] = e;
    lsum += e;
  }
  float gsum = blockSum256(lsum, red);
  float inv = 1.f / gsum;
  float part[DH];
#pragma unroll
  for (int dh = 0; dh < DH; ++dh) part[dh] = 0.f;
  for (int t = threadIdx.x; t < T; t += 256) {
    const float* vp = vbuf + ((size_t)b * T + t) * D + hh * DH;
    float a = sc[t];
#pragma unroll
    for (int dh = 0; dh < DH; ++dh) part[dh] += a * vp[dh];
  }
  for (int dh = 0; dh < DH; ++dh) {
    float tot = blockSum256(part[dh], red);
    if (threadIdx.x == 0)
      ctx[((size_t)b * U + u) * D + hh * DH + dh] = tot * inv;
  }
}

// baseo[b,:] = (mean_u ctx[b,u,:]) @ wo + wo_b
__global__ __launch_bounds__(D) void k_base(const float* __restrict__ ctx,
                                            const float* __restrict__ wo,
                                            const float* __restrict__ wob,
                                            float* __restrict__ baseo) {
  int b = blockIdx.x, d = threadIdx.x;
  __shared__ float bc[D];
  float s = 0.f;
  for (int u = 0; u < U; ++u) s += ctx[((size_t)b * U + u) * D + d];
  bc[d] = s * (1.f / (float)U);
  __syncthreads();
  float acc = wob[d];
  for (int k = 0; k < D; ++k) acc += bc[k] * wo[k * D + d];
  baseo[(size_t)b * D + d] = acc;
}

// ctxo[b,u,:] = ctx[b,u,:] @ wo + wo_b
__global__ __launch_bounds__(D) void k_crow(const float* __restrict__ ctx,
                                            const float* __restrict__ wo,
                                            const float* __restrict__ wob,
                                            float* __restrict__ ctxo) {
  int bu = blockIdx.x, d = threadIdx.x;
  __shared__ float cs[D];
  cs[d] = ctx[(size_t)bu * D + d];
  __syncthreads();
  float acc = wob[d];
  for (int k = 0; k < D; ++k) acc += cs[k] * wo[k * D + d];
  ctxo[(size_t)bu * D + d] = acc;
}

// map[t] = u such that idx[u]==t, else -1
__global__ void k_map(const int* __restrict__ idx, int* __restrict__ map) {
  int t = blockIdx.x * 256 + threadIdx.x;
  if (t >= T) return;
  int m = -1;
  for (int u = 0; u < U; ++u)
    if (idx[u] == t) m = u;
  map[t] = m;
}

// h = LN(h + attn_out)   one block (128 thr) per row
__global__ __launch_bounds__(D) void k_ln1(float* __restrict__ h,
                                           const float* __restrict__ ctxo,
                                           const float* __restrict__ baseo,
                                           const int* __restrict__ map,
                                           const float* __restrict__ g,
                                           const float* __restrict__ bb) {
  int row = blockIdx.x;            // b*T + t
  int b = row >> 10, t = row & (T - 1);
  int d = threadIdx.x;
  int u = map[t];
  float add = (u >= 0) ? ctxo[((size_t)b * U + u) * D + d]
                       : baseo[(size_t)b * D + d];
  float y = h[(size_t)row * D + d] + add;
  __shared__ float red[2];
  float s = y;
  for (int off = 32; off; off >>= 1) s += __shfl_down(s, off);
  if ((threadIdx.x & 63) == 0) red[threadIdx.x >> 6] = s;
  __syncthreads();
  float m = (red[0] + red[1]) * (1.f / D);
  __syncthreads();
  float e = y - m;
  float v = e * e;
  for (int off = 32; off; off >>= 1) v += __shfl_down(v, off);
  if ((threadIdx.x & 63) == 0) red[threadIdx.x >> 6] = v;
  __syncthreads();
  float inv = rsqrtf((red[0] + red[1]) * (1.f / D) + 1e-5f);
  h[(size_t)row * D + d] = e * inv * g[d] + bb[d];
}

// DIAGNOSTIC FF: phase 1 = MFMA f16 (staging+swizzle+fragments+C-map under test),
// phase 2 + residual + LN2 = R1's byte-proven f32 VALU code. 16 rows/block.
constexpr int RF = 16;
__global__ __launch_bounds__(256) void k_ff_diag(
    const float* __restrict__ h,
    const unsigned short* __restrict__ w1t,  // [512][128] f16 (n-major)
    const float* __restrict__ b1,
    const float* __restrict__ w2,            // [512][128] f32 ORIGINAL layout
    const float* __restrict__ b2,
    const float* __restrict__ g,
    const float* __restrict__ bb,
    float* __restrict__ hout) {
  __shared__ unsigned short hsb[RF * 128];   // swizzled f16 A (under test)
  __shared__ float hs[RF][D];                // f32 residual copy
  __shared__ float tmp[RF][FF];              // f32 gelu output, LINEAR (then reused as ys)
  __shared__ float mv[RF][2];

  const int tid = threadIdx.x;
  const int r0 = blockIdx.x * RF;

  // ---- stage h: f32 copy + swizzled f16 copy ----
  {
    int c = tid;                              // 256 chunks, one per thread
    int m = c >> 4, kc = c & 15;
    const float* src = h + (size_t)(r0 + m) * D + kc * 8;
    float4 x0 = *(const float4*)src;
    float4 x1 = *(const float4*)(src + 4);
    *(float4*)&hs[m][kc * 8] = x0;
    *(float4*)&hs[m][kc * 8 + 4] = x1;
    f16x8 p;
    p[0] = (_Float16)x0.x; p[1] = (_Float16)x0.y;
    p[2] = (_Float16)x0.z; p[3] = (_Float16)x0.w;
    p[4] = (_Float16)x1.x; p[5] = (_Float16)x1.y;
    p[6] = (_Float16)x1.z; p[7] = (_Float16)x1.w;
    int byte = (m << 8) + (kc << 4);
    byte ^= (m & 7) << 4;
    *(f16x8*)((char*)hsb + byte) = p;
  }
  __syncthreads();

  const int wv = tid >> 6;
  const int l15 = tid & 15;
  const int lq = (tid & 63) >> 4;

  // A fragments: row = l15, k = ks*32 + lq*8 .. +8
  f16x8 afr[4];
#pragma unroll
  for (int ks = 0; ks < 4; ++ks) {
    int byte = (l15 << 8) + ks * 64 + (lq << 4);
    byte ^= (l15 & 7) << 4;
    afr[ks] = *(const f16x8*)((const char*)hsb + byte);
  }

  // ---- phase 1 (MFMA): tmp = gelu(hs @ w1 + b1), f32 linear store ----
  for (int nt = 0; nt < 8; ++nt) {
    int n0 = wv * 128 + nt * 16;
    const unsigned short* wp = w1t + (size_t)(n0 + l15) * 128 + lq * 8;
    f32x4 acc0 = (f32x4){0.f, 0.f, 0.f, 0.f};
#pragma unroll
    for (int ks = 0; ks < 4; ++ks) {
      f16x8 bf = *(const f16x8*)(wp + ks * 32);
      acc0 = __builtin_amdgcn_mfma_f32_16x16x32_f16(afr[ks], bf, acc0, 0, 0, 0);
    }
    float bcol = b1[n0 + l15];
#pragma unroll
    for (int r = 0; r < 4; ++r) {
      int row0 = 4 * lq + r;                  // C/D: row = 4*(lane>>4)+reg
      float v0 = acc0[r] + bcol;
      v0 = 0.5f * v0 * (1.f + erff(v0 * 0.70710678118654752f));
      tmp[row0][n0 + l15] = v0;               // col = lane&15 (+tile)
    }
  }
  __syncthreads();

  // ---- phase 2 (R1-verbatim f32): y = hs + tmp @ w2 + b2 ----
  int d = tid & 127, half = tid >> 7;
  float acc2[RF / 2];
#pragma unroll
  for (int r = 0; r < RF / 2; ++r) acc2[r] = 0.f;
  for (int k = 0; k < FF; ++k) {
    float w = w2[k * D + d];
#pragma unroll
    for (int r = 0; r < RF / 2; ++r) acc2[r] += tmp[half * (RF / 2) + r][k] * w;
  }
  __syncthreads();                       // done reading tmp; reuse as ys
  float* ys = &tmp[0][0];
  float bd = b2[d];
#pragma unroll
  for (int r = 0; r < RF / 2; ++r) {
    int rr = half * (RF / 2) + r;
    ys[rr * D + d] = hs[rr][d] + acc2[r] + bd;
  }
  __syncthreads();
  // ---- LN2 (R1-verbatim): 16 threads per row ----
  int row = tid >> 4, lane = tid & 15;
  float s = 0.f;
  for (int dd = lane; dd < D; dd += 16) s += ys[row * D + dd];
  for (int off = 8; off; off >>= 1) s += __shfl_down(s, off, 16);
  if (lane == 0) mv[row][0] = s * (1.f / D);
  __syncthreads();
  float m = mv[row][0];
  float v2 = 0.f;
  for (int dd = lane; dd < D; dd += 16) {
    float e = ys[row * D + dd] - m;
    v2 += e * e;
  }
  for (int off = 8; off; off >>= 1) v2 += __shfl_down(v2, off, 16);
  if (lane == 0) mv[row][1] = rsqrtf(v2 * (1.f / D) + 1e-5f);
  __syncthreads();
  for (int i = tid; i < RF * D; i += 256) {
    int r = i / D, dd = i % D;
    hout[(size_t)(r0 + r) * D + dd] = (ys[i] - mv[r][0]) * mv[r][1] * g[dd] + bb[dd];
  }
}

// out[b] = LN(h[b,T-1,:]) @ head_w + head_wb
__global__ __launch_bounds__(D) void k_head(const float* __restrict__ h,
                                            const float* __restrict__ g,
                                            const float* __restrict__ bb,
                                            const float* __restrict__ hw,
                                            const float* __restrict__ hwb,
                                            float* __restrict__ out) {
  int b = blockIdx.x, d = threadIdx.x;
  float y = h[((size_t)b * T + (T - 1)) * D + d];
  __shared__ float red[2];
  float s = y;
  for (int off = 32; off; off >>= 1) s += __shfl_down(s, off);
  if ((threadIdx.x & 63) == 0) red[threadIdx.x >> 6] = s;
  __syncthreads();
  float m = (red[0] + red[1]) * (1.f / D);
  __syncthreads();
  float e = y - m;
  float v = e * e;
  for (int off = 32; off; off >>= 1) v += __shfl_down(v, off);
  if ((threadIdx.x & 63) == 0) red[threadIdx.x >> 6] = v;
  __syncthreads();
  float inv = rsqrtf((red[0] + red[1]) * (1.f / D) + 1e-5f);
  __syncthreads();
  float last = e * inv * g[d] + bb[d];
  float p = last * hw[d];
  for (int off = 32; off; off >>= 1) p += __shfl_down(p, off);
  if ((threadIdx.x & 63) == 0) red[threadIdx.x >> 6] = p;
  __syncthreads();
  if (threadIdx.x == 0) out[b] = red[0] + red[1] + hwb[0];
}

// ---------------- launch ----------------

extern "C" void kernel_launch(void* const* d_in, const int* in_sizes, int n_in,
                              void* d_out, int out_size, void* d_ws, size_t ws_size,
                              hipStream_t stream) {
  const float* x       = (const float*)d_in[0];
  const int*   idx     = (const int*)d_in[1];
  const float* proj_w  = (const float*)d_in[2];
  const float* proj_b  = (const float*)d_in[3];
  const float* wq      = (const float*)d_in[4];
  const float* wk      = (const float*)d_in[5];
  const float* wv      = (const float*)d_in[6];
  const float* wo      = (const float*)d_in[7];
  const float* wo_b    = (const float*)d_in[8];
  const float* ln1_g   = (const float*)d_in[9];
  const float* ln1_b   = (const float*)d_in[10];
  const float* ff1_w   = (const float*)d_in[11];
  const float* ff1_b   = (const float*)d_in[12];
  const float* ff2_w   = (const float*)d_in[13];
  const float* ff2_b   = (const float*)d_in[14];
  const float* ln2_g   = (const float*)d_in[15];
  const float* ln2_b   = (const float*)d_in[16];
  const float* head_g  = (const float*)d_in[17];
  const float* head_bb = (const float*)d_in[18];
  const float* head_w  = (const float*)d_in[19];
  const float* head_wb = (const float*)d_in[20];
  float* out = (float*)d_out;

  float* wsf  = (float*)d_ws;
  float* h    = wsf;
  float* kbuf = h    + (size_t)B * T * D;
  float* vbuf = kbuf + (size_t)B * T * D;
  float* qs   = vbuf + (size_t)B * T * D;
  float* ctx  = qs   + (size_t)B * U * D;
  float* ctxo = ctx  + (size_t)B * U * D;
  float* baseo= ctxo + (size_t)B * U * D;
  int*   map  = (int*)(baseo + (size_t)B * D);
  // f16 w1^T lives INSIDE the qs region (dead between k_attn and next k_qrow)
  // -> total ws footprint identical to the proven R1 layout.
  unsigned short* w1T = (unsigned short*)qs;   // 512*128 ushorts = 128 KB << qs's 2.2 MB

  k_proj<<<B * T, D, 0, stream>>>(x, proj_w, proj_b, h);

  for (int l = 0; l < L; ++l) {
    const float* wq_l = wq + (size_t)l * D * D;
    const float* wk_l = wk + (size_t)l * D * D;
    const float* wv_l = wv + (size_t)l * D * D;
    const float* wo_l = wo + (size_t)l * D * D;
    const int*   idx_l = idx + l * U;

    k_gemm128<<<B * T / 32, 256, 0, stream>>>(h, wk_l, kbuf);
    k_gemm128<<<B * T / 32, 256, 0, stream>>>(h, wv_l, vbuf);
    k_qrow<<<B * U, D, 0, stream>>>(h, idx_l, wq_l, qs);
    k_attn<<<B * H * U, 256, 0, stream>>>(qs, kbuf, vbuf, ctx);
    k_base<<<B, D, 0, stream>>>(ctx, wo_l, wo_b + l * D, baseo);
    k_crow<<<B * U, D, 0, stream>>>(ctx, wo_l, wo_b + l * D, ctxo);
    k_map<<<(T + 255) / 256, 256, 0, stream>>>(idx_l, map);
    k_ln1<<<B * T, D, 0, stream>>>(h, ctxo, baseo, map,
                                   ln1_g + l * D, ln1_b + l * D);
    // qs is dead now (attn consumed it) -> prep this layer's w1^T f16 into it
    k_prep<<<256, 256, 0, stream>>>(ff1_w + (size_t)l * D * FF, w1T, 128, 512);
    k_ff_diag<<<B * T / RF, 256, 0, stream>>>(h, w1T, ff1_b + l * FF,
                                              ff2_w + (size_t)l * FF * D,
                                              ff2_b + l * D,
                                              ln2_g + l * D, ln2_b + l * D, h);
  }

  k_head<<<B, D, 0, stream>>>(h, head_g, head_bb, head_w, head_wb, out);
}